// Round 10
// baseline (885.697 us; speedup 1.0000x reference)
//
#include <hip/hip_runtime.h>
#include <math.h>

#define BGR 256        // graphs
#define NPG0 400       // nodes per graph
#define NN (BGR*NPG0)  // 102400 nodes
#define NE (NN*16)     // 1638400 edges
#define EPG (NPG0*16)  // 6400 edges per graph (contiguous)
#define HD 128
#define AST 416        // adjacency / XT column count (13*32, zero-padded)
#define KSA 13         // agg k-steps
#define MSTR 136       // LDS mean tile row stride (shorts)

typedef __attribute__((ext_vector_type(8))) short short8;
typedef __attribute__((ext_vector_type(4))) float floatx4;

__device__ __forceinline__ unsigned short f2b(float f) {
    unsigned int u = __builtin_bit_cast(unsigned int, f);
    unsigned int r = (u + 0x7fffu + ((u >> 16) & 1u)) >> 16;
    return (unsigned short)r;
}
__device__ __forceinline__ unsigned int pk2(float a, float b) {
    return (unsigned int)f2b(a) | ((unsigned int)f2b(b) << 16);
}
__device__ __forceinline__ float b2f(unsigned short h) {
    return __builtin_bit_cast(float, (unsigned int)h << 16);
}
__device__ __forceinline__ float b2f_lo(unsigned int u) { return __builtin_bit_cast(float, u << 16); }
__device__ __forceinline__ float b2f_hi(unsigned int u) { return __builtin_bit_cast(float, u & 0xffff0000u); }
__device__ __forceinline__ unsigned short bfint(unsigned int v) {
    return (unsigned short)(__builtin_bit_cast(unsigned int, (float)v) >> 16);   // exact for v<256
}

// ---------------- adjacency build: u8 global atomics (stride AST, memset-zeroed)
__global__ void k_abuild(const int* __restrict__ src, const int* __restrict__ dst,
                         unsigned int* __restrict__ A8) {
    int e = blockIdx.x * 256 + threadIdx.x;
    if (e >= NE) return;
    int g = e / EPG;
    int sl = src[e] - g * NPG0;
    int dl = dst[e] - g * NPG0;
    long idx = ((long)g * NPG0 + dl) * AST + sl;
    atomicAdd(&A8[idx >> 2], 1u << ((idx & 3) * 8));
}

// ---------------- u8 -> bf16 adjacency + rowsum -> rliv, alive=1 (one wave per row)
__global__ __launch_bounds__(256) void k_acvt(const unsigned char* __restrict__ A8,
    unsigned short* __restrict__ Abf, float* __restrict__ alive, float* __restrict__ rliv) {
    int wid = threadIdx.x >> 6, lane = threadIdx.x & 63;
    long row = (long)blockIdx.x * 4 + wid;
    const unsigned int* in = (const unsigned int*)(A8 + row * AST);
    unsigned int* outp = (unsigned int*)(Abf + row * AST);
    unsigned int ssum = 0;
    for (int i = lane; i < AST / 4; i += 64) {
        unsigned int u = in[i];
        uint2 o;
        o.x = (unsigned)bfint(u & 0xffu) | ((unsigned)bfint((u >> 8) & 0xffu) << 16);
        o.y = (unsigned)bfint((u >> 16) & 0xffu) | ((unsigned)bfint(u >> 24) << 16);
        *(uint2*)&outp[2 * i] = o;
        unsigned int t1 = (u & 0x00FF00FFu) + ((u >> 8) & 0x00FF00FFu);
        ssum += (t1 & 0xffffu) + (t1 >> 16);
    }
#pragma unroll
    for (int m2 = 1; m2 < 64; m2 <<= 1) ssum += __shfl_xor(ssum, m2);
    if (lane == 0) {
        rliv[row] = 1.0f / fmaxf((float)ssum, 1.0f);
        alive[row] = 1.0f;
    }
}

// ---------------- W -> bf16, transposed (W^T row-major)
__global__ void k_wcvt(const float* __restrict__ c1_wr, const float* __restrict__ c1_ws,
                       const float* __restrict__ cs_wr, const float* __restrict__ cs_ws,
                       unsigned short* __restrict__ bt) {
    int m = blockIdx.y;
    int idx = blockIdx.x * 256 + threadIdx.x;
    const float* W = (m == 0) ? c1_wr : (m == 1) ? c1_ws
                   : (m < 6) ? (cs_wr + (m - 2) * HD * HD) : (cs_ws + (m - 6) * HD * HD);
    int n = idx >> 7, k = idx & 127;
    bt[m * HD * HD + idx] = f2b(W[k * HD + n]);
}

// ---------------- x_in fp32 [node][128] -> XT bf16 [g][f][AST]
__global__ __launch_bounds__(256) void k_xpose(const float* __restrict__ x,
                                               unsigned short* __restrict__ XT) {
    __shared__ unsigned short sT[128 * 104];
    int b = blockIdx.x;
    int g = b >> 2, qq = b & 3;
    int n0 = qq * 100;
    long gn = (long)g * NPG0;
    int t = threadIdx.x;
    for (int idx = t; idx < 100 * 32; idx += 256) {
        int n = idx >> 5, c = idx & 31;
        float4 v = ((const float4*)x)[(gn + n0 + n) * 32 + c];
        sT[(c * 4 + 0) * 104 + n] = f2b(v.x);
        sT[(c * 4 + 1) * 104 + n] = f2b(v.y);
        sT[(c * 4 + 2) * 104 + n] = f2b(v.z);
        sT[(c * 4 + 3) * 104 + n] = f2b(v.w);
    }
    __syncthreads();
    for (int idx = t; idx < 128 * 50; idx += 256) {
        int f = idx / 50, np = idx % 50;
        unsigned int u = (unsigned)sT[f * 104 + 2 * np] | ((unsigned)sT[f * 104 + 2 * np + 1] << 16);
        ((unsigned int*)XT)[((long)g * HD + f) * (AST / 2) + (n0 >> 1) + np] = u;
    }
}

// ---------------- x_in fp32 -> XN bf16 (node-major copy)
__global__ void k_cast(const float* __restrict__ x, unsigned short* __restrict__ XN) {
    long i = (long)blockIdx.x * 256 + threadIdx.x;   // float4 units
    float4 v = ((const float4*)x)[i];
    uint2 w; w.x = pk2(v.x, v.y); w.y = pk2(v.z, v.w);
    ((uint2*)XN)[i] = w;
}

// ---------------- fused layer: 5 blocks/graph (5 tiles each, uniform), 256 thr = 4 waves
// phase C (k-outer): meanT = XT . A^T, acc 5x2 tiles -> sM (normal layout, *rliv)
// phase D (k-outer): OUT = W^T . [mean|x]  (B-ops: sM rows + global XN rows)
// epilogue: relu/alive-gate, write XTout (scalar) + XN in-place (b64), readout, opt dots
__global__ __launch_bounds__(256, 4) void k_layer5(
    const unsigned short* __restrict__ XTin, unsigned short* __restrict__ XTout,
    unsigned short* XN,
    const unsigned short* __restrict__ Abf,
    const float* __restrict__ alive, const float* __restrict__ rliv,
    const unsigned short* __restrict__ wr_bt, const unsigned short* __restrict__ ws_bt,
    const float* __restrict__ bias, float* __restrict__ hcat, int layer,
    const float* __restrict__ pwr, const float* __restrict__ pws,
    float* __restrict__ trg, float* __restrict__ tsg)
{
    __shared__ unsigned short sM[80 * MSTR];
    __shared__ float sTr[4 * 80];
    __shared__ float sTs[4 * 80];
    int t = threadIdx.x;
    int g = blockIdx.x & 255, q = blockIdx.x >> 8;   // q in 0..4; same-graph blocks share XCD
    int ntB = q * 5;
    long gx = (long)g * HD;
    long gn = (long)g * NPG0;
    int lane = t & 63, mp = t >> 6;
    int quad = lane >> 4, l15 = lane & 15;

    // ---- phase C: agg GEMM, k-outer (A-frags 8 regs live, 10 independent acc chains)
    floatx4 acc[5][2];
    floatx4 zz = {0.f, 0.f, 0.f, 0.f};
#pragma unroll
    for (int i = 0; i < 5; ++i) { acc[i][0] = zz; acc[i][1] = zz; }
    const unsigned short* XA0 = &XTin[(gx + 32 * mp + l15) * AST];
    const unsigned short* XA1 = &XTin[(gx + 32 * mp + 16 + l15) * AST];
#pragma unroll
    for (int k = 0; k < KSA; ++k) {
        short8 Af0 = *(const short8*)&XA0[k * 32 + quad * 8];
        short8 Af1 = *(const short8*)&XA1[k * 32 + quad * 8];
#pragma unroll
        for (int i = 0; i < 5; ++i) {
            short8 Bf = *(const short8*)&Abf[(gn + (ntB + i) * 16 + l15) * AST + k * 32 + quad * 8];
            acc[i][0] = __builtin_amdgcn_mfma_f32_16x16x32_bf16(Af0, Bf, acc[i][0], 0, 0, 0);
            acc[i][1] = __builtin_amdgcn_mfma_f32_16x16x32_bf16(Af1, Bf, acc[i][1], 0, 0, 0);
        }
    }
#pragma unroll
    for (int i = 0; i < 5; ++i) {
        float rl = rliv[gn + (ntB + i) * 16 + l15];
        unsigned short* mrow = &sM[(i * 16 + l15) * MSTR + 32 * mp + quad * 4];
        uint2 w0, w1;
        w0.x = pk2(acc[i][0][0] * rl, acc[i][0][1] * rl); w0.y = pk2(acc[i][0][2] * rl, acc[i][0][3] * rl);
        w1.x = pk2(acc[i][1][0] * rl, acc[i][1][1] * rl); w1.y = pk2(acc[i][1][2] * rl, acc[i][1][3] * rl);
        *(uint2*)mrow = w0;
        *(uint2*)(mrow + 16) = w1;
    }
    __syncthreads();

    // ---- phase D: conv GEMM, k-outer
    floatx4 d0[5], d1[5];
    float4 b40 = *(const float4*)&bias[32 * mp + quad * 4];
    float4 b41 = *(const float4*)&bias[32 * mp + 16 + quad * 4];
#pragma unroll
    for (int i = 0; i < 5; ++i) {
        d0[i][0] = b40.x; d0[i][1] = b40.y; d0[i][2] = b40.z; d0[i][3] = b40.w;
        d1[i][0] = b41.x; d1[i][1] = b41.y; d1[i][2] = b41.z; d1[i][3] = b41.w;
    }
#pragma unroll
    for (int k = 0; k < 4; ++k) {
        short8 WrA = *(const short8*)&wr_bt[(32 * mp + l15) * HD + k * 32 + quad * 8];
        short8 WrB = *(const short8*)&wr_bt[(32 * mp + 16 + l15) * HD + k * 32 + quad * 8];
        short8 WsA = *(const short8*)&ws_bt[(32 * mp + l15) * HD + k * 32 + quad * 8];
        short8 WsB = *(const short8*)&ws_bt[(32 * mp + 16 + l15) * HD + k * 32 + quad * 8];
#pragma unroll
        for (int i = 0; i < 5; ++i) {
            short8 B0 = *(const short8*)&sM[(i * 16 + l15) * MSTR + k * 32 + quad * 8];
            short8 B1 = *(const short8*)&XN[(gn + (ntB + i) * 16 + l15) * HD + k * 32 + quad * 8];
            d0[i] = __builtin_amdgcn_mfma_f32_16x16x32_bf16(WrA, B0, d0[i], 0, 0, 0);
            d0[i] = __builtin_amdgcn_mfma_f32_16x16x32_bf16(WsA, B1, d0[i], 0, 0, 0);
            d1[i] = __builtin_amdgcn_mfma_f32_16x16x32_bf16(WrB, B0, d1[i], 0, 0, 0);
            d1[i] = __builtin_amdgcn_mfma_f32_16x16x32_bf16(WsB, B1, d1[i], 0, 0, 0);
        }
    }
    __syncthreads();   // all XN reads complete before in-place writes (cross-wave)

    // ---- epilogue
    bool dodots = trg != nullptr;
    float4 pw0, pw1, pv0, pv1;
    if (dodots) {
        pw0 = *(const float4*)&pwr[32 * mp + quad * 4];
        pw1 = *(const float4*)&pwr[32 * mp + 16 + quad * 4];
        pv0 = *(const float4*)&pws[32 * mp + quad * 4];
        pv1 = *(const float4*)&pws[32 * mp + 16 + quad * 4];
    }
    float ps0[4] = {0, 0, 0, 0}, ps1[4] = {0, 0, 0, 0};
#pragma unroll
    for (int i = 0; i < 5; ++i) {
        int o = (ntB + i) * 16 + l15;
        bool liv = alive[gn + o] != 0.0f;
        float v0r[4], v1r[4];
        float trp = 0.0f, tsp = 0.0f;
#pragma unroll
        for (int rr = 0; rr < 4; ++rr) {
            float v0 = fmaxf(d0[i][rr], 0.0f);
            float v1 = fmaxf(d1[i][rr], 0.0f);
            if (liv) { ps0[rr] += v0; ps1[rr] += v1; }
            else { v0 = 0.0f; v1 = 0.0f; }
            v0r[rr] = v0; v1r[rr] = v1;
            if (dodots) {
                float w0e = (rr == 0) ? pw0.x : (rr == 1) ? pw0.y : (rr == 2) ? pw0.z : pw0.w;
                float w1e = (rr == 0) ? pw1.x : (rr == 1) ? pw1.y : (rr == 2) ? pw1.z : pw1.w;
                float s0e = (rr == 0) ? pv0.x : (rr == 1) ? pv0.y : (rr == 2) ? pv0.z : pv0.w;
                float s1e = (rr == 0) ? pv1.x : (rr == 1) ? pv1.y : (rr == 2) ? pv1.z : pv1.w;
                trp += v0 * w0e + v1 * w1e;
                tsp += v0 * s0e + v1 * s1e;
            }
            XTout[(gx + 32 * mp + quad * 4 + rr) * AST + o] = f2b(v0);
            XTout[(gx + 32 * mp + 16 + quad * 4 + rr) * AST + o] = f2b(v1);
        }
        uint2 wa, wb;
        wa.x = pk2(v0r[0], v0r[1]); wa.y = pk2(v0r[2], v0r[3]);
        wb.x = pk2(v1r[0], v1r[1]); wb.y = pk2(v1r[2], v1r[3]);
        *(uint2*)&XN[(gn + o) * HD + 32 * mp + quad * 4] = wa;
        *(uint2*)&XN[(gn + o) * HD + 32 * mp + 16 + quad * 4] = wb;
        if (dodots) {
            trp += __shfl_xor(trp, 16); trp += __shfl_xor(trp, 32);
            tsp += __shfl_xor(tsp, 16); tsp += __shfl_xor(tsp, 32);
            if (quad == 0) { sTr[mp * 80 + i * 16 + l15] = trp; sTs[mp * 80 + i * 16 + l15] = tsp; }
        }
    }
#pragma unroll
    for (int rr = 0; rr < 4; ++rr) {
        float v = ps0[rr];
        v += __shfl_xor(v, 1); v += __shfl_xor(v, 2); v += __shfl_xor(v, 4); v += __shfl_xor(v, 8);
        float u = ps1[rr];
        u += __shfl_xor(u, 1); u += __shfl_xor(u, 2); u += __shfl_xor(u, 4); u += __shfl_xor(u, 8);
        if (l15 == 0) {
            atomicAdd(&hcat[g * (5 * HD) + layer * HD + 32 * mp + quad * 4 + rr], v);
            atomicAdd(&hcat[g * (5 * HD) + layer * HD + 32 * mp + 16 + quad * 4 + rr], u);
        }
    }
    if (dodots) {
        __syncthreads();
        if (t < 80) {
            trg[gn + ntB * 16 + t] = sTr[t] + sTr[80 + t] + sTr[160 + t] + sTr[240 + t];
            tsg[gn + ntB * 16 + t] = sTs[t] + sTs[80 + t] + sTs[160 + t] + sTs[240 + t];
        }
    }
}

// ---------------- score (parallel): score[d] = (A[d].tr)*rliv + ts + pb  (dead -> -inf)
__global__ __launch_bounds__(256) void k_score(const unsigned short* __restrict__ Abf,
    const float* __restrict__ trb, const float* __restrict__ tsb,
    const float* __restrict__ alive, const float* __restrict__ rliv,
    const float* __restrict__ pb, float* __restrict__ score)
{
    __shared__ float str[AST];
    int b = blockIdx.x;
    int g = b / 25, r0 = (b % 25) * 16;
    long gn = (long)g * NPG0;
    int t = threadIdx.x;
    for (int i = t; i < AST; i += 256) str[i] = (i < NPG0) ? trb[gn + i] : 0.0f;
    __syncthreads();
    int lane = t & 63, w = t >> 6;
    float pbv = pb[0];
    for (int rr = 0; rr < 4; ++rr) {
        int row = r0 + w * 4 + rr;
        const unsigned int* Ar = (const unsigned int*)(Abf + (gn + row) * AST);
        float acc = 0.0f;
#pragma unroll
        for (int it = 0; it < 4; ++it) {
            int i = it * 64 + lane;
            if (i < AST / 2) {
                unsigned int a = Ar[i];
                float2 tv = ((const float2*)str)[i];
                acc = fmaf(b2f_lo(a), tv.x, acc);
                acc = fmaf(b2f_hi(a), tv.y, acc);
            }
        }
#pragma unroll
        for (int m2 = 1; m2 < 64; m2 <<= 1) acc += __shfl_xor(acc, m2);
        if (lane == 0) {
            float v = (alive[gn + row] != 0.0f)
                    ? acc * rliv[gn + row] + tsb[gn + row] + pbv : -INFINITY;
            score[gn + row] = v;
        }
    }
}

// ---------------- rliv (parallel): rliv[d] = 1/max(A[d].alive, 1)
__global__ __launch_bounds__(256) void k_rlivk(const unsigned short* __restrict__ Abf,
    const float* __restrict__ alive, float* __restrict__ rliv)
{
    __shared__ float skf[AST];
    int b = blockIdx.x;
    int g = b / 25, r0 = (b % 25) * 16;
    long gn = (long)g * NPG0;
    int t = threadIdx.x;
    for (int i = t; i < AST; i += 256) skf[i] = (i < NPG0) ? alive[gn + i] : 0.0f;
    __syncthreads();
    int lane = t & 63, w = t >> 6;
    for (int rr = 0; rr < 4; ++rr) {
        int row = r0 + w * 4 + rr;
        const unsigned int* Ar = (const unsigned int*)(Abf + (gn + row) * AST);
        float acc = 0.0f;
#pragma unroll
        for (int it = 0; it < 4; ++it) {
            int i = it * 64 + lane;
            if (i < AST / 2) {
                unsigned int a = Ar[i];
                float2 kv = ((const float2*)skf)[i];
                acc = fmaf(b2f_lo(a), kv.x, acc);
                acc = fmaf(b2f_hi(a), kv.y, acc);
            }
        }
#pragma unroll
        for (int m2 = 1; m2 < 64; m2 <<= 1) acc += __shfl_xor(acc, m2);
        if (lane == 0) rliv[gn + row] = 1.0f / fmaxf(acc, 1.0f);
    }
}

// ---------------- per-graph sort: top-K threshold, keep (lowest-index ties), mult, alive
__global__ __launch_bounds__(256) void k_sort(const float* __restrict__ score,
    float* __restrict__ alive, float* __restrict__ multg, int K)
{
    __shared__ float s[512];
    __shared__ float sc[NPG0];
    __shared__ unsigned char keep[NPG0];
    __shared__ int cnt_gt;
    int g = blockIdx.x, t = threadIdx.x;
    long gn = (long)g * NPG0;
    for (int i = t; i < 512; i += 256) {
        float v = (i < NPG0) ? score[gn + i] : -INFINITY;
        s[i] = v;
        if (i < NPG0) sc[i] = v;
    }
    if (t == 0) cnt_gt = 0;
    __syncthreads();
    for (int ksz = 2; ksz <= 512; ksz <<= 1) {
        for (int jsz = ksz >> 1; jsz >= 1; jsz >>= 1) {
            for (int i = t; i < 512; i += 256) {
                int ixj = i ^ jsz;
                if (ixj > i) {
                    float a = s[i], c = s[ixj];
                    bool up = ((i & ksz) == 0);
                    if ((a > c) == up) { s[i] = c; s[ixj] = a; }
                }
            }
            __syncthreads();
        }
    }
    float thr = s[512 - K];
    for (int n = t; n < NPG0; n += 256)
        if (sc[n] > thr) atomicAdd(&cnt_gt, 1);
    __syncthreads();
    if (t == 0) {   // tie-break: lowest index (matches lax.top_k)
        int m = K - cnt_gt, tk = 0;
        for (int n = 0; n < NPG0; n++) {
            bool kp = sc[n] > thr;
            if (!kp && sc[n] == thr && tk < m) { kp = true; tk++; }
            keep[n] = kp ? 1 : 0;
        }
    }
    __syncthreads();
    for (int n = t; n < NPG0; n += 256) {
        bool kp = keep[n] != 0;
        multg[gn + n] = kp ? tanhf(sc[n]) : 0.0f;
        alive[gn + n] = kp ? 1.0f : 0.0f;
    }
}

// ---------------- XT scale: XT[g][f][n] *= mult[g*NPG0+n]; pads -> 0
__global__ __launch_bounds__(256) void k_scale(unsigned short* __restrict__ XT,
                                               const float* __restrict__ multg) {
    long idx = (long)blockIdx.x * 256 + threadIdx.x;   // u32 units
    int cpair = (int)(idx % (AST / 2));
    int gf = (int)(idx / (AST / 2));
    int g = gf >> 7;
    int n0 = 2 * cpair;
    unsigned int* p = &((unsigned int*)XT)[idx];
    unsigned int u = *p;
    float m0 = (n0 < NPG0) ? multg[(long)g * NPG0 + n0] : 0.0f;
    float m1 = (n0 + 1 < NPG0) ? multg[(long)g * NPG0 + n0 + 1] : 0.0f;
    *p = pk2(b2f_lo(u) * m0, b2f_hi(u) * m1);
}

// ---------------- XN scale: XN[node][f] *= mult[node]
__global__ __launch_bounds__(256) void k_scalen(unsigned short* __restrict__ XN,
                                                const float* __restrict__ multg) {
    long idx = (long)blockIdx.x * 256 + threadIdx.x;   // uint2 units (4 bf16)
    int node = (int)(idx >> 5);
    float m = multg[node];
    uint2* p = &((uint2*)XN)[idx];
    uint2 u = *p;
    uint2 w;
    w.x = pk2(b2f_lo(u.x) * m, b2f_hi(u.x) * m);
    w.y = pk2(b2f_lo(u.y) * m, b2f_hi(u.y) * m);
    *p = w;
}

// ---------------- final MLP + log_softmax (hcat holds SUMS; divide here)
__global__ __launch_bounds__(256) void k_mlp(const float* __restrict__ h, const float* __restrict__ w1,
    const float* __restrict__ b1, const float* __restrict__ w2,
    const float* __restrict__ b2, float* __restrict__ out) {
    __shared__ float shg[5 * HD];
    __shared__ float prt[256];
    __shared__ float h1[HD];
    __shared__ float red[HD];
    __shared__ float lg[2];
    const float inv[5] = {1.0f/400.0f, 1.0f/400.0f, 1.0f/320.0f, 1.0f/320.0f, 1.0f/256.0f};
    int g = blockIdx.x, t = threadIdx.x;
    for (int k = t; k < 5 * HD; k += 256) shg[k] = h[g * (5 * HD) + k] * inv[k >> 7];
    __syncthreads();
    int j = t & 127, half = t >> 7;
    float acc = half ? 0.0f : b1[j];
    for (int k = half * 320; k < half * 320 + 320; ++k)
        acc = fmaf(shg[k], w1[k * HD + j], acc);
    prt[t] = acc;
    __syncthreads();
    if (t < HD) h1[t] = fmaxf(prt[t] + prt[t + 128], 0.0f);
    __syncthreads();
    for (int c = 0; c < 2; c++) {
        if (t < HD) red[t] = h1[t] * w2[t * 2 + c];
        __syncthreads();
        for (int st = 64; st > 0; st >>= 1) {
            if (t < st) red[t] += red[t + st];
            __syncthreads();
        }
        if (t == 0) lg[c] = red[0] + b2[c];
        __syncthreads();
    }
    if (t == 0) {
        float l0 = lg[0], l1 = lg[1];
        float m = fmaxf(l0, l1);
        float lse = m + logf(expf(l0 - m) + expf(l1 - m));
        out[g * 2 + 0] = l0 - lse;
        out[g * 2 + 1] = l1 - lse;
    }
}

extern "C" void kernel_launch(void* const* d_in, const int* in_sizes, int n_in,
                              void* d_out, int out_size, void* d_ws, size_t ws_size,
                              hipStream_t stream) {
    const float* x_in   = (const float*)d_in[0];
    const int*   eidx   = (const int*)d_in[1];
    const int*   e_src  = eidx;
    const int*   e_dst  = eidx + NE;
    const float* c1_wr  = (const float*)d_in[3];
    const float* c1_ws  = (const float*)d_in[4];
    const float* c1_b   = (const float*)d_in[5];
    const float* cs_wr  = (const float*)d_in[6];
    const float* cs_ws  = (const float*)d_in[7];
    const float* cs_b   = (const float*)d_in[8];
    const float* p_wr   = (const float*)d_in[9];
    const float* p_ws   = (const float*)d_in[10];
    const float* p_b    = (const float*)d_in[11];
    const float* l1_w   = (const float*)d_in[12];
    const float* l1_b   = (const float*)d_in[13];
    const float* l2_w   = (const float*)d_in[14];
    const float* l2_b   = (const float*)d_in[15];
    float* out = (float*)d_out;

    char* ws = (char*)d_ws;
    size_t off = 0;
    float* alive = (float*)(ws + off);                 off += (size_t)NN * 4;
    float* rliv  = (float*)(ws + off);                 off += (size_t)NN * 4;
    float* hcat  = (float*)(ws + off);                 off += (size_t)BGR * 5 * HD * 4;
    unsigned short* wbt = (unsigned short*)(ws + off); off += (size_t)10 * HD * HD * 2;
    unsigned short* Abf = (unsigned short*)(ws + off); off += (size_t)NN * AST * 2;
    unsigned short* XT0 = (unsigned short*)(ws + off); off += (size_t)BGR * HD * AST * 2;
    unsigned short* XT1 = (unsigned short*)(ws + off); off += (size_t)BGR * HD * AST * 2;
    unsigned short* XN  = (unsigned short*)(ws + off); off += (size_t)NN * HD * 2;
    float* trb   = (float*)(ws + off);                 off += (size_t)NN * 4;
    float* tsb   = (float*)(ws + off);                 off += (size_t)NN * 4;
    float* scoreb = (float*)(ws + off);                off += (size_t)NN * 4;
    float* multb = (float*)(ws + off);                 off += (size_t)NN * 4;
    unsigned char* A8 = (unsigned char*)XT0;           // aliases XT0/XT1; dead after k_acvt

    hipMemsetAsync(A8, 0, (size_t)NN * AST, stream);
    hipMemsetAsync(hcat, 0, (size_t)BGR * 5 * HD * 4, stream);
    k_abuild<<<NE / 256, 256, 0, stream>>>(e_src, e_dst, (unsigned int*)A8);
    k_acvt<<<NN / 4, 256, 0, stream>>>(A8, Abf, alive, rliv);
    k_wcvt<<<dim3(64, 10), 256, 0, stream>>>(c1_wr, c1_ws, cs_wr, cs_ws, wbt);
    k_xpose<<<BGR * 4, 256, 0, stream>>>(x_in, XT0);   // overwrites A8 head (dead)
    k_cast<<<NN * 32 / 256, 256, 0, stream>>>(x_in, XN);

    unsigned short* bt_wr[5] = { wbt + 0 * HD * HD, wbt + 2 * HD * HD, wbt + 3 * HD * HD, wbt + 4 * HD * HD, wbt + 5 * HD * HD };
    unsigned short* bt_ws[5] = { wbt + 1 * HD * HD, wbt + 6 * HD * HD, wbt + 7 * HD * HD, wbt + 8 * HD * HD, wbt + 9 * HD * HD };
    int sgrid = (int)(((long)BGR * HD * (AST / 2)) / 256);

    // conv1: XT0 -> XT1, XN in-place
    k_layer5<<<BGR * 5, 256, 0, stream>>>(XT0, XT1, XN, Abf, alive, rliv,
        bt_wr[0], bt_ws[0], c1_b, hcat, 0, nullptr, nullptr, nullptr, nullptr);
    // convs[0]: XT1 -> XT0 (+ pool-0 dots)
    k_layer5<<<BGR * 5, 256, 0, stream>>>(XT1, XT0, XN, Abf, alive, rliv,
        bt_wr[1], bt_ws[1], cs_b + 0 * HD, hcat, 1, p_wr + 0 * HD, p_ws + 0 * HD, trb, tsb);
    // pool 0 (K=320)
    k_score<<<BGR * 25, 256, 0, stream>>>(Abf, trb, tsb, alive, rliv, p_b + 0, scoreb);
    k_sort<<<BGR, 256, 0, stream>>>(scoreb, alive, multb, 320);
    k_rlivk<<<BGR * 25, 256, 0, stream>>>(Abf, alive, rliv);
    k_scale<<<sgrid, 256, 0, stream>>>(XT0, multb);
    k_scalen<<<NN * 32 / 256, 256, 0, stream>>>(XN, multb);
    // convs[1]: XT0 -> XT1
    k_layer5<<<BGR * 5, 256, 0, stream>>>(XT0, XT1, XN, Abf, alive, rliv,
        bt_wr[2], bt_ws[2], cs_b + 1 * HD, hcat, 2, nullptr, nullptr, nullptr, nullptr);
    // convs[2]: XT1 -> XT0 (+ pool-1 dots)
    k_layer5<<<BGR * 5, 256, 0, stream>>>(XT1, XT0, XN, Abf, alive, rliv,
        bt_wr[3], bt_ws[3], cs_b + 2 * HD, hcat, 3, p_wr + 1 * HD, p_ws + 1 * HD, trb, tsb);
    // pool 1 (K=256)
    k_score<<<BGR * 25, 256, 0, stream>>>(Abf, trb, tsb, alive, rliv, p_b + 1, scoreb);
    k_sort<<<BGR, 256, 0, stream>>>(scoreb, alive, multb, 256);
    k_rlivk<<<BGR * 25, 256, 0, stream>>>(Abf, alive, rliv);
    k_scale<<<sgrid, 256, 0, stream>>>(XT0, multb);
    k_scalen<<<NN * 32 / 256, 256, 0, stream>>>(XN, multb);
    // convs[3]: XT0 -> XT1
    k_layer5<<<BGR * 5, 256, 0, stream>>>(XT0, XT1, XN, Abf, alive, rliv,
        bt_wr[4], bt_ws[4], cs_b + 3 * HD, hcat, 4, nullptr, nullptr, nullptr, nullptr);
    // MLP head
    k_mlp<<<BGR, 256, 0, stream>>>(hcat, l1_w, l1_b, l2_w, l2_b, out);
}